// Round 13
// baseline (406.850 us; speedup 1.0000x reference)
//
#include <hip/hip_runtime.h>
#include <math.h>

#define NN 100000
#define EE 1600000
#define GG 64
#define NCLS 10

#define BSH 8                 // bucket = dst >> 8 (256 nodes per bucket)
#define NB 391                // ceil(NN / 256)
#define BCAP 4608             // fixed bucket capacity (mean 4092, sigma 64 -> 8 sigma)
#define EPS 4096              // edges per block in bscatter
#define CAPS 5120             // bsort LDS staging capacity (ints)

typedef unsigned int uint32;

__device__ __forceinline__ unsigned short f2bf(float f) {
    unsigned u = __float_as_uint(f);
    unsigned r = (u + 0x7fffu + ((u >> 16) & 1u)) >> 16;   // RNE
    return (unsigned short)r;
}

// ---------------- CSR build: slot-bucket counting sort (no global hist/scan) ----------------

__global__ __launch_bounds__(512) void bscatter_kernel(
    const int* __restrict__ src, const int* __restrict__ dst,
    int* __restrict__ bfill, uint32* __restrict__ bpack, int n) {
    __shared__ int hist[512], gbase[512], lbase[512], cnt2[512];
    __shared__ int wtot[8];
    __shared__ uint32 lsd[EPS];
    __shared__ unsigned short bkt[EPS];
    int tid = threadIdx.x;
    int lane = tid & 63, wv = tid >> 6;
    int e0 = blockIdx.x * EPS;
    int e1 = min(e0 + EPS, n);

    hist[tid] = 0;
    cnt2[tid] = 0;
    __syncthreads();
    for (int e = e0 + tid; e < e1; e += 512) atomicAdd(&hist[dst[e] >> BSH], 1);
    __syncthreads();
    int h = hist[tid];
    int inc = h;
#pragma unroll
    for (int off = 1; off < 64; off <<= 1) {
        int t = __shfl_up(inc, off);
        if (lane >= off) inc += t;
    }
    if (lane == 63) wtot[wv] = inc;
    __syncthreads();
    if (tid < 8) {
        int t = wtot[tid];
#pragma unroll
        for (int off = 1; off < 8; off <<= 1) {
            int u = __shfl_up(t, off, 8);
            if (tid >= off) t += u;
        }
        wtot[tid] = t;
    }
    __syncthreads();
    if (wv > 0) inc += wtot[wv - 1];
    int lb = inc - h;
    lbase[tid] = lb;
    int go = h > 0 ? atomicAdd(&bfill[tid], h) : 0;
    gbase[tid] = tid * BCAP + go - lb;   // g = gbase[b] + slot
    __syncthreads();
    for (int e = e0 + tid; e < e1; e += 512) {
        int s = src[e], dd = dst[e];
        int b = dd >> BSH;
        int r = atomicAdd(&cnt2[b], 1);
        int slot = lbase[b] + r;
        lsd[slot] = ((uint32)s << 8) | (uint32)(dd & 255);
        bkt[slot] = (unsigned short)b;
    }
    __syncthreads();
    int m = e1 - e0;
    for (int i = tid; i < m; i += 512)
        bpack[gbase[bkt[i]] + i] = lsd[i];
}

// per-bucket counting sort -> rp/re + col (slotted, base = b*BCAP)
__global__ __launch_bounds__(256) void bsort_kernel(
    const uint32* __restrict__ bpack, const int* __restrict__ bfill,
    int* __restrict__ rp, int* __restrict__ re, int* __restrict__ col) {
    __shared__ int cnt[256], cnt2[256];
    __shared__ int wtot[4];
    __shared__ int stage[CAPS];
    int b = blockIdx.x;
    int tid = threadIdx.x;
    int ebeg = b * BCAP;
    int sz = bfill[b];                // real edge count (pad slots never touched)
    int n0 = b << BSH;
    int nn = min(256, NN - n0);

    cnt[tid] = 0;
    cnt2[tid] = 0;
    __syncthreads();
    const uint4* bq = (const uint4*)(bpack + ebeg);
    int nq = sz >> 2;
    for (int i = tid; i < nq; i += 256) {
        uint4 p = bq[i];
        atomicAdd(&cnt[p.x & 255u], 1);
        atomicAdd(&cnt[p.y & 255u], 1);
        atomicAdd(&cnt[p.z & 255u], 1);
        atomicAdd(&cnt[p.w & 255u], 1);
    }
    for (int e = (nq << 2) + tid; e < sz; e += 256)
        atomicAdd(&cnt[bpack[ebeg + e] & 255u], 1);
    __syncthreads();
    int lane = tid & 63, wv = tid >> 6;
    int c = cnt[tid];
    int inc = c;
#pragma unroll
    for (int off = 1; off < 64; off <<= 1) {
        int t = __shfl_up(inc, off);
        if (lane >= off) inc += t;
    }
    if (lane == 63) wtot[wv] = inc;
    __syncthreads();
    if (tid < 4) {
        int t = wtot[tid];
#pragma unroll
        for (int off = 1; off < 4; off <<= 1) {
            int u = __shfl_up(t, off, 4);
            if (tid >= off) t += u;
        }
        wtot[tid] = t;
    }
    __syncthreads();
    if (wv > 0) inc += wtot[wv - 1];
    int excl = inc - c;
    cnt[tid] = excl;  // reuse cnt as exclusive offsets
    if (tid < nn) {
        rp[n0 + tid] = ebeg + excl;
        re[n0 + tid] = ebeg + inc;
    }
    __syncthreads();
    bool fits = sz <= CAPS;
    for (int i = tid; i < nq; i += 256) {
        uint4 p = bq[i];
        int d0 = (int)(p.x & 255u), d1 = (int)(p.y & 255u);
        int d2 = (int)(p.z & 255u), d3 = (int)(p.w & 255u);
        int p0 = cnt[d0] + atomicAdd(&cnt2[d0], 1);
        int p1 = cnt[d1] + atomicAdd(&cnt2[d1], 1);
        int p2 = cnt[d2] + atomicAdd(&cnt2[d2], 1);
        int p3 = cnt[d3] + atomicAdd(&cnt2[d3], 1);
        if (fits) {
            stage[p0] = (int)(p.x >> 8); stage[p1] = (int)(p.y >> 8);
            stage[p2] = (int)(p.z >> 8); stage[p3] = (int)(p.w >> 8);
        } else {
            col[ebeg + p0] = (int)(p.x >> 8); col[ebeg + p1] = (int)(p.y >> 8);
            col[ebeg + p2] = (int)(p.z >> 8); col[ebeg + p3] = (int)(p.w >> 8);
        }
    }
    for (int e = (nq << 2) + tid; e < sz; e += 256) {
        uint32 p = bpack[ebeg + e];
        int dl = (int)(p & 255u);
        int pos = cnt[dl] + atomicAdd(&cnt2[dl], 1);
        if (fits) stage[pos] = (int)(p >> 8);
        else col[ebeg + pos] = (int)(p >> 8);
    }
    __syncthreads();
    if (fits) {
        uint4* colq = (uint4*)(col + ebeg);
        const uint4* stq = (const uint4*)stage;
        for (int i = tid; i < nq; i += 256) colq[i] = stq[i];
        for (int i = (nq << 2) + tid; i < sz; i += 256) col[ebeg + i] = stage[i];
    }
}

// ---------------- GEMM h = X @ W (+ attention logits), bf16 H output ----------------

template <int K>
__global__ __launch_bounds__(256) void gemm_al_kernel(
    const float* __restrict__ X, const float* __restrict__ W,
    const float* __restrict__ a_src, const float* __restrict__ a_dst,
    unsigned short* __restrict__ H, float* __restrict__ ALs, float* __restrict__ ALd,
    int nrows) {
    const int KP = K + 4;
    __shared__ float Xs[64 * (K + 4)];
    __shared__ float Ws[K * 64];
    int tid = threadIdx.x;
    int r0 = blockIdx.x * 64;

    {
        const float4* Wg = (const float4*)W;
        float4* Ws4 = (float4*)Ws;
        for (int i = tid; i < K * 16; i += 256) Ws4[i] = Wg[i];
    }
    {
        const float4* Xg = (const float4*)(X + (size_t)r0 * K);
        const int nq = 64 * K / 4;
        int valid_q = (min(64, nrows - r0) * K) / 4;
        const int QPR = K / 4;  // quads per row
        for (int i = tid; i < nq; i += 256) {
            int row = i / QPR, wq = i % QPR;
            float4 v = (i < valid_q) ? Xg[i] : make_float4(0.f, 0.f, 0.f, 0.f);
            *(float4*)&Xs[row * KP + wq * 4] = v;
        }
    }
    __syncthreads();

    int cg = tid & 15, rg = tid >> 4;
    int rbase = rg * 4;
    float4 acc0 = make_float4(0.f, 0.f, 0.f, 0.f);
    float4 acc1 = acc0, acc2 = acc0, acc3 = acc0;

#pragma unroll 2
    for (int k = 0; k < K; k += 4) {
        float4 x0 = *(const float4*)&Xs[(rbase + 0) * KP + k];
        float4 x1 = *(const float4*)&Xs[(rbase + 1) * KP + k];
        float4 x2 = *(const float4*)&Xs[(rbase + 2) * KP + k];
        float4 x3 = *(const float4*)&Xs[(rbase + 3) * KP + k];
        float4 w0 = *(const float4*)&Ws[(k + 0) * 64 + 4 * cg];
        float4 w1 = *(const float4*)&Ws[(k + 1) * 64 + 4 * cg];
        float4 w2 = *(const float4*)&Ws[(k + 2) * 64 + 4 * cg];
        float4 w3 = *(const float4*)&Ws[(k + 3) * 64 + 4 * cg];
#define FMA4(A, S, WV) \
        A.x = fmaf(S, WV.x, A.x); A.y = fmaf(S, WV.y, A.y); \
        A.z = fmaf(S, WV.z, A.z); A.w = fmaf(S, WV.w, A.w)
        FMA4(acc0, x0.x, w0); FMA4(acc1, x1.x, w0); FMA4(acc2, x2.x, w0); FMA4(acc3, x3.x, w0);
        FMA4(acc0, x0.y, w1); FMA4(acc1, x1.y, w1); FMA4(acc2, x2.y, w1); FMA4(acc3, x3.y, w1);
        FMA4(acc0, x0.z, w2); FMA4(acc1, x1.z, w2); FMA4(acc2, x2.z, w2); FMA4(acc3, x3.z, w2);
        FMA4(acc0, x0.w, w3); FMA4(acc1, x1.w, w3); FMA4(acc2, x2.w, w3); FMA4(acc3, x3.w, w3);
#undef FMA4
    }

    int hh = cg >> 1;
    float4 as4 = ((const float4*)a_src)[cg];
    float4 ad4 = ((const float4*)a_dst)[cg];
    float4 accs[4] = {acc0, acc1, acc2, acc3};
#pragma unroll
    for (int i = 0; i < 4; ++i) {
        int r = r0 + rbase + i;
        if (r < nrows) {
            ushort4 p;
            p.x = f2bf(accs[i].x); p.y = f2bf(accs[i].y);
            p.z = f2bf(accs[i].z); p.w = f2bf(accs[i].w);
            ((ushort4*)H)[(size_t)r * 16 + cg] = p;   // row = 64 bf16 = 16 ushort4
            float ps = accs[i].x * as4.x + accs[i].y * as4.y +
                       accs[i].z * as4.z + accs[i].w * as4.w;
            float pd = accs[i].x * ad4.x + accs[i].y * ad4.y +
                       accs[i].z * ad4.z + accs[i].w * ad4.w;
            ps += __shfl_xor(ps, 1);
            pd += __shfl_xor(pd, 1);
            if ((cg & 1) == 0) {
                ALs[r * 8 + hh] = ps;
                ALd[r * 8 + hh] = pd;
            }
        }
    }
}

// ---------------- GAT aggregation: lane-per-(node,head), bf16 H gather ----------------
// Wave = 8 nodes x 8 heads. x8 chunks with ALL col loads hoisted ahead of the
// gathers: the data dependence forces 8 cols live -> 8-load burst, then 16
// independent gathers in flight. (256,4) bound gives VGPR headroom (~128).

__global__ __launch_bounds__(256, 4) void agg_kernel(
    const unsigned short* __restrict__ H, const float* __restrict__ ALs,
    const float* __restrict__ ALd, const int* __restrict__ rp,
    const int* __restrict__ re, const int* __restrict__ col,
    const float* __restrict__ bias, float* __restrict__ Out, int n) {
    int tid = threadIdx.x;
    int lane = tid & 63;
    int slot = lane >> 3, head = lane & 7;
    int wid = blockIdx.x * 4 + (tid >> 6);
    int d = wid * 8 + slot;
    bool active = d < n;
    if (!active) d = n - 1;
    const uint4* __restrict__ Hq = (const uint4*)H;   // row = 8 uint4

    float ad = ALd[d * 8 + head];
    float acc0 = 0.f, acc1 = 0.f, acc2 = 0.f, acc3 = 0.f;
    float acc4 = 0.f, acc5 = 0.f, acc6 = 0.f, acc7 = 0.f;
    float wsum = 0.f;

#define FMA8(U, W) { \
    acc0 = fmaf(W, __uint_as_float((U).x << 16), acc0); \
    acc1 = fmaf(W, __uint_as_float((U).x & 0xffff0000u), acc1); \
    acc2 = fmaf(W, __uint_as_float((U).y << 16), acc2); \
    acc3 = fmaf(W, __uint_as_float((U).y & 0xffff0000u), acc3); \
    acc4 = fmaf(W, __uint_as_float((U).z << 16), acc4); \
    acc5 = fmaf(W, __uint_as_float((U).z & 0xffff0000u), acc5); \
    acc6 = fmaf(W, __uint_as_float((U).w << 16), acc6); \
    acc7 = fmaf(W, __uint_as_float((U).w & 0xffff0000u), acc7); }

    {   // self loop
        uint4 u = Hq[(size_t)d * 8 + head];
        float e = ALs[d * 8 + head] + ad;
        e = fmaxf(e, 0.2f * e);
        float w = __expf(e);
        FMA8(u, w);
        wsum = w;
    }

    int k = rp[d], kend = re[d];
    for (; k + 8 <= kend; k += 8) {
        // hoisted col burst (8 independent loads, one wait)
        int s0 = col[k],     s1 = col[k + 1], s2 = col[k + 2], s3 = col[k + 3];
        int s4 = col[k + 4], s5 = col[k + 5], s6 = col[k + 6], s7 = col[k + 7];
        // 16 independent gathers
        uint4 u0 = Hq[(size_t)s0 * 8 + head];
        uint4 u1 = Hq[(size_t)s1 * 8 + head];
        uint4 u2 = Hq[(size_t)s2 * 8 + head];
        uint4 u3 = Hq[(size_t)s3 * 8 + head];
        uint4 u4 = Hq[(size_t)s4 * 8 + head];
        uint4 u5 = Hq[(size_t)s5 * 8 + head];
        uint4 u6 = Hq[(size_t)s6 * 8 + head];
        uint4 u7 = Hq[(size_t)s7 * 8 + head];
        float a0 = ALs[s0 * 8 + head], a1 = ALs[s1 * 8 + head];
        float a2 = ALs[s2 * 8 + head], a3 = ALs[s3 * 8 + head];
        float a4 = ALs[s4 * 8 + head], a5 = ALs[s5 * 8 + head];
        float a6 = ALs[s6 * 8 + head], a7 = ALs[s7 * 8 + head];
        float e0 = a0 + ad; e0 = fmaxf(e0, 0.2f * e0); float w0 = __expf(e0);
        float e1 = a1 + ad; e1 = fmaxf(e1, 0.2f * e1); float w1 = __expf(e1);
        float e2 = a2 + ad; e2 = fmaxf(e2, 0.2f * e2); float w2 = __expf(e2);
        float e3 = a3 + ad; e3 = fmaxf(e3, 0.2f * e3); float w3 = __expf(e3);
        float e4 = a4 + ad; e4 = fmaxf(e4, 0.2f * e4); float w4 = __expf(e4);
        float e5 = a5 + ad; e5 = fmaxf(e5, 0.2f * e5); float w5 = __expf(e5);
        float e6 = a6 + ad; e6 = fmaxf(e6, 0.2f * e6); float w6 = __expf(e6);
        float e7 = a7 + ad; e7 = fmaxf(e7, 0.2f * e7); float w7 = __expf(e7);
        FMA8(u0, w0); FMA8(u1, w1); FMA8(u2, w2); FMA8(u3, w3);
        FMA8(u4, w4); FMA8(u5, w5); FMA8(u6, w6); FMA8(u7, w7);
        wsum += (w0 + w1) + (w2 + w3) + (w4 + w5) + (w6 + w7);
    }
    if (k + 4 <= kend) {
        int s0 = col[k], s1 = col[k + 1], s2 = col[k + 2], s3 = col[k + 3];
        uint4 u0 = Hq[(size_t)s0 * 8 + head];
        uint4 u1 = Hq[(size_t)s1 * 8 + head];
        uint4 u2 = Hq[(size_t)s2 * 8 + head];
        uint4 u3 = Hq[(size_t)s3 * 8 + head];
        float a0 = ALs[s0 * 8 + head], a1 = ALs[s1 * 8 + head];
        float a2 = ALs[s2 * 8 + head], a3 = ALs[s3 * 8 + head];
        float e0 = a0 + ad; e0 = fmaxf(e0, 0.2f * e0); float w0 = __expf(e0);
        float e1 = a1 + ad; e1 = fmaxf(e1, 0.2f * e1); float w1 = __expf(e1);
        float e2 = a2 + ad; e2 = fmaxf(e2, 0.2f * e2); float w2 = __expf(e2);
        float e3 = a3 + ad; e3 = fmaxf(e3, 0.2f * e3); float w3 = __expf(e3);
        FMA8(u0, w0); FMA8(u1, w1); FMA8(u2, w2); FMA8(u3, w3);
        wsum += (w0 + w1) + (w2 + w3);
        k += 4;
    }
    if (k + 2 <= kend) {
        int s0 = col[k], s1 = col[k + 1];
        uint4 u0 = Hq[(size_t)s0 * 8 + head];
        uint4 u1 = Hq[(size_t)s1 * 8 + head];
        float a0 = ALs[s0 * 8 + head], a1 = ALs[s1 * 8 + head];
        float e0 = a0 + ad; e0 = fmaxf(e0, 0.2f * e0); float w0 = __expf(e0);
        float e1 = a1 + ad; e1 = fmaxf(e1, 0.2f * e1); float w1 = __expf(e1);
        FMA8(u0, w0); FMA8(u1, w1);
        wsum += w0 + w1;
        k += 2;
    }
    if (k < kend) {
        int s = col[k];
        uint4 u = Hq[(size_t)s * 8 + head];
        float a = ALs[s * 8 + head];
        float e = a + ad; e = fmaxf(e, 0.2f * e);
        float w = __expf(e);
        FMA8(u, w);
        wsum += w;
    }
#undef FMA8

    if (active) {
        float inv = 1.f / wsum;
        float4 b0 = ((const float4*)bias)[head * 2];
        float4 b1 = ((const float4*)bias)[head * 2 + 1];
        float4 o0, o1;
        o0.x = fmaf(acc0, inv, b0.x); o0.x = o0.x > 0.f ? o0.x : expm1f(o0.x);
        o0.y = fmaf(acc1, inv, b0.y); o0.y = o0.y > 0.f ? o0.y : expm1f(o0.y);
        o0.z = fmaf(acc2, inv, b0.z); o0.z = o0.z > 0.f ? o0.z : expm1f(o0.z);
        o0.w = fmaf(acc3, inv, b0.w); o0.w = o0.w > 0.f ? o0.w : expm1f(o0.w);
        o1.x = fmaf(acc4, inv, b1.x); o1.x = o1.x > 0.f ? o1.x : expm1f(o1.x);
        o1.y = fmaf(acc5, inv, b1.y); o1.y = o1.y > 0.f ? o1.y : expm1f(o1.y);
        o1.z = fmaf(acc6, inv, b1.z); o1.z = o1.z > 0.f ? o1.z : expm1f(o1.z);
        o1.w = fmaf(acc7, inv, b1.w); o1.w = o1.w > 0.f ? o1.w : expm1f(o1.w);
        ((float4*)Out)[(size_t)d * 16 + head * 2] = o0;
        ((float4*)Out)[(size_t)d * 16 + head * 2 + 1] = o1;
    }
}

// ---------------- global mean pool (batch is sorted) ----------------

__global__ void pool_kernel(const float* __restrict__ H, const int* __restrict__ batch,
                            float* __restrict__ sums, float* __restrict__ cnt, int n) {
    int gw = (int)((blockIdx.x * blockDim.x + threadIdx.x) >> 6);
    int lane = threadIdx.x & 63;
    int n0 = gw * 64;
    if (n0 >= n) return;
    int n1 = min(n0 + 64, n);
    int curb = batch[n0];
    float local = 0.f, c_local = 0.f;
    for (int i = n0; i < n1; ++i) {
        int b = batch[i];
        if (b != curb) {
            atomicAdd(&sums[curb * 64 + lane], local);
            if (lane == 0) atomicAdd(&cnt[curb], c_local);
            local = 0.f;
            c_local = 0.f;
            curb = b;
        }
        local += H[(size_t)i * 64 + lane];
        c_local += 1.f;
    }
    atomicAdd(&sums[curb * 64 + lane], local);
    if (lane == 0) atomicAdd(&cnt[curb], c_local);
}

__global__ void final_kernel(const float* __restrict__ sums, const float* __restrict__ cnt,
                             const float* __restrict__ W, const float* __restrict__ b,
                             float* __restrict__ out) {
    int t = blockIdx.x * blockDim.x + threadIdx.x;
    if (t >= GG * NCLS) return;
    int g = t / NCLS, k = t % NCLS;
    float c = cnt[g];
    if (c < 1.f) c = 1.f;
    float inv = 1.f / c;
    float acc = b[k];
#pragma unroll
    for (int cc = 0; cc < 64; ++cc)
        acc = fmaf(sums[g * 64 + cc] * inv, W[cc * NCLS + k], acc);
    out[t] = acc;
}

// ---------------- launch ----------------

extern "C" void kernel_launch(void* const* d_in, const int* in_sizes, int n_in,
                              void* d_out, int out_size, void* d_ws, size_t ws_size,
                              hipStream_t stream) {
    const float* x    = (const float*)d_in[0];
    const int*   ei   = (const int*)d_in[1];   // [2,E]: src = ei, dst = ei+EE
    const int*   batch = (const int*)d_in[2];
    const float* W1 = (const float*)d_in[3];
    const float* a1s = (const float*)d_in[4];
    const float* a1d = (const float*)d_in[5];
    const float* b1 = (const float*)d_in[6];
    const float* W2 = (const float*)d_in[7];
    const float* a2s = (const float*)d_in[8];
    const float* a2d = (const float*)d_in[9];
    const float* b2 = (const float*)d_in[10];
    const float* W3 = (const float*)d_in[11];
    const float* a3s = (const float*)d_in[12];
    const float* a3d = (const float*)d_in[13];
    const float* b3 = (const float*)d_in[14];
    const float* linW = (const float*)d_in[15];
    const float* linb = (const float*)d_in[16];
    float* out = (float*)d_out;

    char* ws = (char*)d_ws;
    size_t off = 0;
    auto alloc = [&](size_t bytes) -> void* {
        void* p = ws + off;
        off = (off + bytes + 255) & ~(size_t)255;
        return p;
    };
    unsigned short* hBf = (unsigned short*)alloc((size_t)NN * 64 * 2);  // bf16 projected features
    float* hF     = (float*)alloc((size_t)NN * 64 * 4);                  // fp32 layer outputs
    float* ALs    = (float*)alloc((size_t)NN * 8 * 4);
    float* ALd    = (float*)alloc((size_t)NN * 8 * 4);
    int*   rp     = (int*)alloc((size_t)NN * 4);
    int*   reArr  = (int*)alloc((size_t)NN * 4);
    int*   bfill  = (int*)alloc((size_t)NB * 4);
    uint32* bpack = (uint32*)alloc((size_t)NB * BCAP * 4);
    int*   col    = (int*)alloc((size_t)NB * BCAP * 4);
    float* sums   = (float*)alloc((size_t)(GG * 64 + GG) * 4);
    float* gcnt   = sums + GG * 64;

    const int NBLK = (NN + 255) / 256;
    const int SB = (EE + EPS - 1) / EPS;   // 391

    hipMemsetAsync(bfill, 0, (size_t)NB * 4, stream);
    bscatter_kernel<<<SB, 512, 0, stream>>>(ei, ei + EE, bfill, bpack, EE);
    bsort_kernel<<<NB, 256, 0, stream>>>(bpack, bfill, rp, reArr, col);

    const int GB = (NN + 63) / 64;    // 1563 blocks, 64 rows each
    const int AB = (NN + 31) / 32;    // 3125 blocks, 32 nodes each

    gemm_al_kernel<128><<<GB, 256, 0, stream>>>(x, W1, a1s, a1d, hBf, ALs, ALd, NN);
    agg_kernel<<<AB, 256, 0, stream>>>(hBf, ALs, ALd, rp, reArr, col, b1, hF, NN);

    gemm_al_kernel<64><<<GB, 256, 0, stream>>>(hF, W2, a2s, a2d, hBf, ALs, ALd, NN);
    agg_kernel<<<AB, 256, 0, stream>>>(hBf, ALs, ALd, rp, reArr, col, b2, hF, NN);

    gemm_al_kernel<64><<<GB, 256, 0, stream>>>(hF, W3, a3s, a3d, hBf, ALs, ALd, NN);
    agg_kernel<<<AB, 256, 0, stream>>>(hBf, ALs, ALd, rp, reArr, col, b3, hF, NN);

    hipMemsetAsync(sums, 0, (size_t)(GG * 64 + GG) * 4, stream);
    pool_kernel<<<NBLK, 256, 0, stream>>>(hF, batch, sums, gcnt, NN);
    final_kernel<<<3, 256, 0, stream>>>(sums, gcnt, linW, linb, out);
}

// Round 14
// 394.666 us; speedup vs baseline: 1.0309x; 1.0309x over previous
//
#include <hip/hip_runtime.h>
#include <math.h>

#define NN 100000
#define EE 1600000
#define GG 64
#define NCLS 10

#define BSH 8                 // bucket = dst >> 8 (256 nodes per bucket)
#define NB 391                // ceil(NN / 256)
#define BCAP 4608             // fixed bucket capacity (mean 4092, sigma 64 -> 8 sigma)
#define EPS 4096              // edges per block in bscatter
#define CAPS 5120             // bsort LDS staging capacity (ints)

typedef unsigned int uint32;

__device__ __forceinline__ unsigned short f2bf(float f) {
    unsigned u = __float_as_uint(f);
    unsigned r = (u + 0x7fffu + ((u >> 16) & 1u)) >> 16;   // RNE
    return (unsigned short)r;
}

// ---------------- CSR build: slot-bucket counting sort (no global hist/scan) ----------------

__global__ __launch_bounds__(512) void bscatter_kernel(
    const int* __restrict__ src, const int* __restrict__ dst,
    int* __restrict__ bfill, uint32* __restrict__ bpack, int n) {
    __shared__ int hist[512], gbase[512], lbase[512], cnt2[512];
    __shared__ int wtot[8];
    __shared__ uint32 lsd[EPS];
    __shared__ unsigned short bkt[EPS];
    int tid = threadIdx.x;
    int lane = tid & 63, wv = tid >> 6;
    int e0 = blockIdx.x * EPS;
    int e1 = min(e0 + EPS, n);

    hist[tid] = 0;
    cnt2[tid] = 0;
    __syncthreads();
    for (int e = e0 + tid; e < e1; e += 512) atomicAdd(&hist[dst[e] >> BSH], 1);
    __syncthreads();
    int h = hist[tid];
    int inc = h;
#pragma unroll
    for (int off = 1; off < 64; off <<= 1) {
        int t = __shfl_up(inc, off);
        if (lane >= off) inc += t;
    }
    if (lane == 63) wtot[wv] = inc;
    __syncthreads();
    if (tid < 8) {
        int t = wtot[tid];
#pragma unroll
        for (int off = 1; off < 8; off <<= 1) {
            int u = __shfl_up(t, off, 8);
            if (tid >= off) t += u;
        }
        wtot[tid] = t;
    }
    __syncthreads();
    if (wv > 0) inc += wtot[wv - 1];
    int lb = inc - h;
    lbase[tid] = lb;
    int go = h > 0 ? atomicAdd(&bfill[tid], h) : 0;
    gbase[tid] = tid * BCAP + go - lb;   // g = gbase[b] + slot
    __syncthreads();
    for (int e = e0 + tid; e < e1; e += 512) {
        int s = src[e], dd = dst[e];
        int b = dd >> BSH;
        int r = atomicAdd(&cnt2[b], 1);
        int slot = lbase[b] + r;
        lsd[slot] = ((uint32)s << 8) | (uint32)(dd & 255);
        bkt[slot] = (unsigned short)b;
    }
    __syncthreads();
    int m = e1 - e0;
    for (int i = tid; i < m; i += 512)
        bpack[gbase[bkt[i]] + i] = lsd[i];
}

// per-bucket counting sort -> rp/re + col (slotted, base = b*BCAP)
__global__ __launch_bounds__(256) void bsort_kernel(
    const uint32* __restrict__ bpack, const int* __restrict__ bfill,
    int* __restrict__ rp, int* __restrict__ re, int* __restrict__ col) {
    __shared__ int cnt[256], cnt2[256];
    __shared__ int wtot[4];
    __shared__ int stage[CAPS];
    int b = blockIdx.x;
    int tid = threadIdx.x;
    int ebeg = b * BCAP;
    int sz = bfill[b];                // real edge count (pad slots never touched)
    int n0 = b << BSH;
    int nn = min(256, NN - n0);

    cnt[tid] = 0;
    cnt2[tid] = 0;
    __syncthreads();
    const uint4* bq = (const uint4*)(bpack + ebeg);
    int nq = sz >> 2;
    for (int i = tid; i < nq; i += 256) {
        uint4 p = bq[i];
        atomicAdd(&cnt[p.x & 255u], 1);
        atomicAdd(&cnt[p.y & 255u], 1);
        atomicAdd(&cnt[p.z & 255u], 1);
        atomicAdd(&cnt[p.w & 255u], 1);
    }
    for (int e = (nq << 2) + tid; e < sz; e += 256)
        atomicAdd(&cnt[bpack[ebeg + e] & 255u], 1);
    __syncthreads();
    int lane = tid & 63, wv = tid >> 6;
    int c = cnt[tid];
    int inc = c;
#pragma unroll
    for (int off = 1; off < 64; off <<= 1) {
        int t = __shfl_up(inc, off);
        if (lane >= off) inc += t;
    }
    if (lane == 63) wtot[wv] = inc;
    __syncthreads();
    if (tid < 4) {
        int t = wtot[tid];
#pragma unroll
        for (int off = 1; off < 4; off <<= 1) {
            int u = __shfl_up(t, off, 4);
            if (tid >= off) t += u;
        }
        wtot[tid] = t;
    }
    __syncthreads();
    if (wv > 0) inc += wtot[wv - 1];
    int excl = inc - c;
    cnt[tid] = excl;  // reuse cnt as exclusive offsets
    if (tid < nn) {
        rp[n0 + tid] = ebeg + excl;
        re[n0 + tid] = ebeg + inc;
    }
    __syncthreads();
    bool fits = sz <= CAPS;
    for (int i = tid; i < nq; i += 256) {
        uint4 p = bq[i];
        int d0 = (int)(p.x & 255u), d1 = (int)(p.y & 255u);
        int d2 = (int)(p.z & 255u), d3 = (int)(p.w & 255u);
        int p0 = cnt[d0] + atomicAdd(&cnt2[d0], 1);
        int p1 = cnt[d1] + atomicAdd(&cnt2[d1], 1);
        int p2 = cnt[d2] + atomicAdd(&cnt2[d2], 1);
        int p3 = cnt[d3] + atomicAdd(&cnt2[d3], 1);
        if (fits) {
            stage[p0] = (int)(p.x >> 8); stage[p1] = (int)(p.y >> 8);
            stage[p2] = (int)(p.z >> 8); stage[p3] = (int)(p.w >> 8);
        } else {
            col[ebeg + p0] = (int)(p.x >> 8); col[ebeg + p1] = (int)(p.y >> 8);
            col[ebeg + p2] = (int)(p.z >> 8); col[ebeg + p3] = (int)(p.w >> 8);
        }
    }
    for (int e = (nq << 2) + tid; e < sz; e += 256) {
        uint32 p = bpack[ebeg + e];
        int dl = (int)(p & 255u);
        int pos = cnt[dl] + atomicAdd(&cnt2[dl], 1);
        if (fits) stage[pos] = (int)(p >> 8);
        else col[ebeg + pos] = (int)(p >> 8);
    }
    __syncthreads();
    if (fits) {
        uint4* colq = (uint4*)(col + ebeg);
        const uint4* stq = (const uint4*)stage;
        for (int i = tid; i < nq; i += 256) colq[i] = stq[i];
        for (int i = (nq << 2) + tid; i < sz; i += 256) col[ebeg + i] = stage[i];
    }
}

// ---------------- GEMM h = X @ W (+ attention logits), bf16 H output ----------------
// Register-tiled 64x64 tile, 4x4 per thread. Split-K staging: Xs holds a 64-wide
// K-chunk (64 x 68 floats, bank-pad +4) restaged per chunk; Ws staged fully once.
// K=128 LDS: 17.4+32.8 = 50.2 KB -> 3 blocks/CU (was 66.5 KB -> 2).

template <int K>
__global__ __launch_bounds__(256) void gemm_al_kernel(
    const float* __restrict__ X, const float* __restrict__ W,
    const float* __restrict__ a_src, const float* __restrict__ a_dst,
    unsigned short* __restrict__ H, float* __restrict__ ALs, float* __restrict__ ALd,
    int nrows) {
    const int KC = 64;            // K-chunk width
    const int KP = KC + 4;        // padded row stride (bank fix)
    __shared__ float Xs[64 * (KC + 4)];
    __shared__ float Ws[K * 64];
    int tid = threadIdx.x;
    int r0 = blockIdx.x * 64;
    int validRows = min(64, nrows - r0);

    {
        const float4* Wg = (const float4*)W;
        float4* Ws4 = (float4*)Ws;
        for (int i = tid; i < K * 16; i += 256) Ws4[i] = Wg[i];
    }

    int cg = tid & 15, rg = tid >> 4;
    int rbase = rg * 4;
    float4 acc0 = make_float4(0.f, 0.f, 0.f, 0.f);
    float4 acc1 = acc0, acc2 = acc0, acc3 = acc0;

    const float4* Xg = (const float4*)X;
    const int QG = K / 4;        // float4s per global row

    for (int kc = 0; kc < K; kc += KC) {
        __syncthreads();   // all waves done with previous chunk (and Ws staged, 1st iter)
        // stage 64-row x 64-col chunk (16 float4 per row)
        for (int i = tid; i < 64 * 16; i += 256) {
            int row = i >> 4, q = i & 15;
            float4 v = (row < validRows)
                ? Xg[(size_t)(r0 + row) * QG + (kc >> 2) + q]
                : make_float4(0.f, 0.f, 0.f, 0.f);
            *(float4*)&Xs[row * KP + q * 4] = v;
        }
        __syncthreads();

#pragma unroll 2
        for (int k = 0; k < KC; k += 4) {
            float4 x0 = *(const float4*)&Xs[(rbase + 0) * KP + k];
            float4 x1 = *(const float4*)&Xs[(rbase + 1) * KP + k];
            float4 x2 = *(const float4*)&Xs[(rbase + 2) * KP + k];
            float4 x3 = *(const float4*)&Xs[(rbase + 3) * KP + k];
            float4 w0 = *(const float4*)&Ws[(kc + k + 0) * 64 + 4 * cg];
            float4 w1 = *(const float4*)&Ws[(kc + k + 1) * 64 + 4 * cg];
            float4 w2 = *(const float4*)&Ws[(kc + k + 2) * 64 + 4 * cg];
            float4 w3 = *(const float4*)&Ws[(kc + k + 3) * 64 + 4 * cg];
#define FMA4(A, S, WV) \
            A.x = fmaf(S, WV.x, A.x); A.y = fmaf(S, WV.y, A.y); \
            A.z = fmaf(S, WV.z, A.z); A.w = fmaf(S, WV.w, A.w)
            FMA4(acc0, x0.x, w0); FMA4(acc1, x1.x, w0); FMA4(acc2, x2.x, w0); FMA4(acc3, x3.x, w0);
            FMA4(acc0, x0.y, w1); FMA4(acc1, x1.y, w1); FMA4(acc2, x2.y, w1); FMA4(acc3, x3.y, w1);
            FMA4(acc0, x0.z, w2); FMA4(acc1, x1.z, w2); FMA4(acc2, x2.z, w2); FMA4(acc3, x3.z, w2);
            FMA4(acc0, x0.w, w3); FMA4(acc1, x1.w, w3); FMA4(acc2, x2.w, w3); FMA4(acc3, x3.w, w3);
#undef FMA4
        }
    }

    int hh = cg >> 1;
    float4 as4 = ((const float4*)a_src)[cg];
    float4 ad4 = ((const float4*)a_dst)[cg];
    float4 accs[4] = {acc0, acc1, acc2, acc3};
#pragma unroll
    for (int i = 0; i < 4; ++i) {
        int r = r0 + rbase + i;
        if (r < nrows) {
            ushort4 p;
            p.x = f2bf(accs[i].x); p.y = f2bf(accs[i].y);
            p.z = f2bf(accs[i].z); p.w = f2bf(accs[i].w);
            ((ushort4*)H)[(size_t)r * 16 + cg] = p;   // row = 64 bf16 = 16 ushort4
            float ps = accs[i].x * as4.x + accs[i].y * as4.y +
                       accs[i].z * as4.z + accs[i].w * as4.w;
            float pd = accs[i].x * ad4.x + accs[i].y * ad4.y +
                       accs[i].z * ad4.z + accs[i].w * ad4.w;
            ps += __shfl_xor(ps, 1);
            pd += __shfl_xor(pd, 1);
            if ((cg & 1) == 0) {
                ALs[r * 8 + hh] = ps;
                ALd[r * 8 + hh] = pd;
            }
        }
    }
}

// ---------------- GAT aggregation: lane-per-(node,head), bf16 H gather ----------------
// Wave = 8 nodes x 8 heads. R12-proven version: plain col loads, x4 unroll, (256,6).

__global__ __launch_bounds__(256, 6) void agg_kernel(
    const unsigned short* __restrict__ H, const float* __restrict__ ALs,
    const float* __restrict__ ALd, const int* __restrict__ rp,
    const int* __restrict__ re, const int* __restrict__ col,
    const float* __restrict__ bias, float* __restrict__ Out, int n) {
    int tid = threadIdx.x;
    int lane = tid & 63;
    int slot = lane >> 3, head = lane & 7;
    int wid = blockIdx.x * 4 + (tid >> 6);
    int d = wid * 8 + slot;
    bool active = d < n;
    if (!active) d = n - 1;
    const uint4* __restrict__ Hq = (const uint4*)H;   // row = 8 uint4

    float ad = ALd[d * 8 + head];
    float acc0 = 0.f, acc1 = 0.f, acc2 = 0.f, acc3 = 0.f;
    float acc4 = 0.f, acc5 = 0.f, acc6 = 0.f, acc7 = 0.f;
    float wsum = 0.f;

#define FMA8(U, W) { \
    acc0 = fmaf(W, __uint_as_float((U).x << 16), acc0); \
    acc1 = fmaf(W, __uint_as_float((U).x & 0xffff0000u), acc1); \
    acc2 = fmaf(W, __uint_as_float((U).y << 16), acc2); \
    acc3 = fmaf(W, __uint_as_float((U).y & 0xffff0000u), acc3); \
    acc4 = fmaf(W, __uint_as_float((U).z << 16), acc4); \
    acc5 = fmaf(W, __uint_as_float((U).z & 0xffff0000u), acc5); \
    acc6 = fmaf(W, __uint_as_float((U).w << 16), acc6); \
    acc7 = fmaf(W, __uint_as_float((U).w & 0xffff0000u), acc7); }

    {   // self loop
        uint4 u = Hq[(size_t)d * 8 + head];
        float e = ALs[d * 8 + head] + ad;
        e = fmaxf(e, 0.2f * e);
        float w = __expf(e);
        FMA8(u, w);
        wsum = w;
    }

    int k = rp[d], kend = re[d];
    for (; k + 4 <= kend; k += 4) {
        int s0 = col[k], s1 = col[k + 1], s2 = col[k + 2], s3 = col[k + 3];
        uint4 u0 = Hq[(size_t)s0 * 8 + head];
        uint4 u1 = Hq[(size_t)s1 * 8 + head];
        uint4 u2 = Hq[(size_t)s2 * 8 + head];
        uint4 u3 = Hq[(size_t)s3 * 8 + head];
        float a0 = ALs[s0 * 8 + head];
        float a1 = ALs[s1 * 8 + head];
        float a2 = ALs[s2 * 8 + head];
        float a3 = ALs[s3 * 8 + head];
        float e0 = a0 + ad; e0 = fmaxf(e0, 0.2f * e0); float w0 = __expf(e0);
        float e1 = a1 + ad; e1 = fmaxf(e1, 0.2f * e1); float w1 = __expf(e1);
        float e2 = a2 + ad; e2 = fmaxf(e2, 0.2f * e2); float w2 = __expf(e2);
        float e3 = a3 + ad; e3 = fmaxf(e3, 0.2f * e3); float w3 = __expf(e3);
        FMA8(u0, w0);
        FMA8(u1, w1);
        FMA8(u2, w2);
        FMA8(u3, w3);
        wsum += (w0 + w1) + (w2 + w3);
    }
    if (k + 2 <= kend) {
        int s0 = col[k], s1 = col[k + 1];
        uint4 u0 = Hq[(size_t)s0 * 8 + head];
        uint4 u1 = Hq[(size_t)s1 * 8 + head];
        float a0 = ALs[s0 * 8 + head];
        float a1 = ALs[s1 * 8 + head];
        float e0 = a0 + ad; e0 = fmaxf(e0, 0.2f * e0); float w0 = __expf(e0);
        float e1 = a1 + ad; e1 = fmaxf(e1, 0.2f * e1); float w1 = __expf(e1);
        FMA8(u0, w0);
        FMA8(u1, w1);
        wsum += w0 + w1;
        k += 2;
    }
    if (k < kend) {
        int s = col[k];
        uint4 u = Hq[(size_t)s * 8 + head];
        float a = ALs[s * 8 + head];
        float e = a + ad; e = fmaxf(e, 0.2f * e);
        float w = __expf(e);
        FMA8(u, w);
        wsum += w;
    }
#undef FMA8

    if (active) {
        float inv = 1.f / wsum;
        float4 b0 = ((const float4*)bias)[head * 2];
        float4 b1 = ((const float4*)bias)[head * 2 + 1];
        float4 o0, o1;
        o0.x = fmaf(acc0, inv, b0.x); o0.x = o0.x > 0.f ? o0.x : expm1f(o0.x);
        o0.y = fmaf(acc1, inv, b0.y); o0.y = o0.y > 0.f ? o0.y : expm1f(o0.y);
        o0.z = fmaf(acc2, inv, b0.z); o0.z = o0.z > 0.f ? o0.z : expm1f(o0.z);
        o0.w = fmaf(acc3, inv, b0.w); o0.w = o0.w > 0.f ? o0.w : expm1f(o0.w);
        o1.x = fmaf(acc4, inv, b1.x); o1.x = o1.x > 0.f ? o1.x : expm1f(o1.x);
        o1.y = fmaf(acc5, inv, b1.y); o1.y = o1.y > 0.f ? o1.y : expm1f(o1.y);
        o1.z = fmaf(acc6, inv, b1.z); o1.z = o1.z > 0.f ? o1.z : expm1f(o1.z);
        o1.w = fmaf(acc7, inv, b1.w); o1.w = o1.w > 0.f ? o1.w : expm1f(o1.w);
        ((float4*)Out)[(size_t)d * 16 + head * 2] = o0;
        ((float4*)Out)[(size_t)d * 16 + head * 2 + 1] = o1;
    }
}

// ---------------- global mean pool (batch is sorted) ----------------

__global__ void pool_kernel(const float* __restrict__ H, const int* __restrict__ batch,
                            float* __restrict__ sums, float* __restrict__ cnt, int n) {
    int gw = (int)((blockIdx.x * blockDim.x + threadIdx.x) >> 6);
    int lane = threadIdx.x & 63;
    int n0 = gw * 64;
    if (n0 >= n) return;
    int n1 = min(n0 + 64, n);
    int curb = batch[n0];
    float local = 0.f, c_local = 0.f;
    for (int i = n0; i < n1; ++i) {
        int b = batch[i];
        if (b != curb) {
            atomicAdd(&sums[curb * 64 + lane], local);
            if (lane == 0) atomicAdd(&cnt[curb], c_local);
            local = 0.f;
            c_local = 0.f;
            curb = b;
        }
        local += H[(size_t)i * 64 + lane];
        c_local += 1.f;
    }
    atomicAdd(&sums[curb * 64 + lane], local);
    if (lane == 0) atomicAdd(&cnt[curb], c_local);
}

__global__ void final_kernel(const float* __restrict__ sums, const float* __restrict__ cnt,
                             const float* __restrict__ W, const float* __restrict__ b,
                             float* __restrict__ out) {
    int t = blockIdx.x * blockDim.x + threadIdx.x;
    if (t >= GG * NCLS) return;
    int g = t / NCLS, k = t % NCLS;
    float c = cnt[g];
    if (c < 1.f) c = 1.f;
    float inv = 1.f / c;
    float acc = b[k];
#pragma unroll
    for (int cc = 0; cc < 64; ++cc)
        acc = fmaf(sums[g * 64 + cc] * inv, W[cc * NCLS + k], acc);
    out[t] = acc;
}

// ---------------- launch ----------------

extern "C" void kernel_launch(void* const* d_in, const int* in_sizes, int n_in,
                              void* d_out, int out_size, void* d_ws, size_t ws_size,
                              hipStream_t stream) {
    const float* x    = (const float*)d_in[0];
    const int*   ei   = (const int*)d_in[1];   // [2,E]: src = ei, dst = ei+EE
    const int*   batch = (const int*)d_in[2];
    const float* W1 = (const float*)d_in[3];
    const float* a1s = (const float*)d_in[4];
    const float* a1d = (const float*)d_in[5];
    const float* b1 = (const float*)d_in[6];
    const float* W2 = (const float*)d_in[7];
    const float* a2s = (const float*)d_in[8];
    const float* a2d = (const float*)d_in[9];
    const float* b2 = (const float*)d_in[10];
    const float* W3 = (const float*)d_in[11];
    const float* a3s = (const float*)d_in[12];
    const float* a3d = (const float*)d_in[13];
    const float* b3 = (const float*)d_in[14];
    const float* linW = (const float*)d_in[15];
    const float* linb = (const float*)d_in[16];
    float* out = (float*)d_out;

    char* ws = (char*)d_ws;
    size_t off = 0;
    auto alloc = [&](size_t bytes) -> void* {
        void* p = ws + off;
        off = (off + bytes + 255) & ~(size_t)255;
        return p;
    };
    unsigned short* hBf = (unsigned short*)alloc((size_t)NN * 64 * 2);  // bf16 projected features
    float* hF     = (float*)alloc((size_t)NN * 64 * 4);                  // fp32 layer outputs
    float* ALs    = (float*)alloc((size_t)NN * 8 * 4);
    float* ALd    = (float*)alloc((size_t)NN * 8 * 4);
    int*   rp     = (int*)alloc((size_t)NN * 4);
    int*   reArr  = (int*)alloc((size_t)NN * 4);
    int*   bfill  = (int*)alloc((size_t)NB * 4);
    uint32* bpack = (uint32*)alloc((size_t)NB * BCAP * 4);
    int*   col    = (int*)alloc((size_t)NB * BCAP * 4);
    float* sums   = (float*)alloc((size_t)(GG * 64 + GG) * 4);
    float* gcnt   = sums + GG * 64;

    const int NBLK = (NN + 255) / 256;
    const int SB = (EE + EPS - 1) / EPS;   // 391

    hipMemsetAsync(bfill, 0, (size_t)NB * 4, stream);
    bscatter_kernel<<<SB, 512, 0, stream>>>(ei, ei + EE, bfill, bpack, EE);
    bsort_kernel<<<NB, 256, 0, stream>>>(bpack, bfill, rp, reArr, col);

    const int GB = (NN + 63) / 64;    // 1563 blocks, 64 rows each
    const int AB = (NN + 31) / 32;    // 3125 blocks, 32 nodes each

    gemm_al_kernel<128><<<GB, 256, 0, stream>>>(x, W1, a1s, a1d, hBf, ALs, ALd, NN);
    agg_kernel<<<AB, 256, 0, stream>>>(hBf, ALs, ALd, rp, reArr, col, b1, hF, NN);

    gemm_al_kernel<64><<<GB, 256, 0, stream>>>(hF, W2, a2s, a2d, hBf, ALs, ALd, NN);
    agg_kernel<<<AB, 256, 0, stream>>>(hBf, ALs, ALd, rp, reArr, col, b2, hF, NN);

    gemm_al_kernel<64><<<GB, 256, 0, stream>>>(hF, W3, a3s, a3d, hBf, ALs, ALd, NN);
    agg_kernel<<<AB, 256, 0, stream>>>(hBf, ALs, ALd, rp, reArr, col, b3, hF, NN);

    hipMemsetAsync(sums, 0, (size_t)(GG * 64 + GG) * 4, stream);
    pool_kernel<<<NBLK, 256, 0, stream>>>(hF, batch, sums, gcnt, NN);
    final_kernel<<<3, 256, 0, stream>>>(sums, gcnt, linW, linb, out);
}